// Round 3
// baseline (402.501 us; speedup 1.0000x reference)
//
#include <hip/hip_runtime.h>
#include <stdint.h>

#define BATCH 8
#define NLEAF 64
#define VOCAB 128000
#define ROW (NLEAF * VOCAB)        // 8,192,000
#define CHUNK 4096
#define NCHUNK (ROW / CHUNK)       // 2000 4096-chunks per row
#define SUB 512                    // VOCAB % 512 == 0 -> sub-chunk never crosses a leaf
#define NSUB (ROW / SUB)           // 16000 sub-chunks per row
#define TOPK 64

// ---------------------------------------------------------------------------
// Kernel 1: mandatory 262MB read. One block = one 4096-chunk = 8 sub-chunks
// of 512. Each 32-lane group owns one sub-chunk (single leaf -> uniform p).
// Emits per-512 max (for a tight threshold) and per-4096 max (for collect's
// early exit). max(p*a_i) == p*max(a_i) bit-exactly for p>=0 (monotone mul).
// ---------------------------------------------------------------------------
__global__ __launch_bounds__(256) void k_chunkmax(
    const float* __restrict__ sp, const float* __restrict__ pp,
    float* __restrict__ cmax512, float* __restrict__ cmax4096)
{
    int c   = blockIdx.x;            // 0 .. BATCH*NCHUNK-1
    int row = c / NCHUNK;
    int cr  = c - row * NCHUNK;
    long base = (long)row * ROW + (long)cr * CHUNK;
    int fr    = cr * CHUNK;          // row-local flat base

    int t = threadIdx.x;
    int g = t >> 5;                  // sub-chunk 0..7
    int l = t & 31;
    int subfr = fr + g * SUB;        // row-local, multiple of 512 -> one leaf
    float p = pp[row * NLEAF + subfr / VOCAB];

    const float4* sp4 = (const float4*)(sp + base + g * SUB);
    float m = 0.f;                   // inputs are uniform(0,1) >= 0
#pragma unroll
    for (int i = 0; i < 4; ++i) {
        float4 v = sp4[l + i * 32];
        m = fmaxf(m, fmaxf(fmaxf(v.x, v.y), fmaxf(v.z, v.w)));
    }
    for (int off = 16; off; off >>= 1) m = fmaxf(m, __shfl_down(m, off, 32));

    __shared__ float s[8];
    if (l == 0) {
        float pm = p * m;
        cmax512[(long)row * NSUB + cr * 8 + g] = pm;
        s[g] = pm;
    }
    __syncthreads();
    if (t == 0) {
        float mm = s[0];
#pragma unroll
        for (int i = 1; i < 8; ++i) mm = fmaxf(mm, s[i]);
        cmax4096[c] = mm;
    }
}

// ---------------------------------------------------------------------------
// Kernel 2: per row, EXACT 64th-largest 512-chunk max via 4-level radix
// select on float bits (values >= 0 so uint order == float order).
// 16000 values staged in LDS (64KB). Also zeroes the candidate counter.
// ---------------------------------------------------------------------------
__global__ __launch_bounds__(256) void k_threshold(
    const float* __restrict__ cmax512, float* __restrict__ thr,
    int* __restrict__ cnt)
{
    int row = blockIdx.x;
    int t = threadIdx.x;
    __shared__ unsigned uv[NSUB];
    __shared__ int hist[256], sc[256];
    __shared__ unsigned s_prefix;
    __shared__ int s_k;
    for (int i = t; i < NSUB; i += 256)
        uv[i] = __float_as_uint(cmax512[(long)row * NSUB + i]);
    if (t == 0) { cnt[row] = 0; s_prefix = 0u; s_k = TOPK; }
    __syncthreads();

    for (int level = 3; level >= 0; --level) {
        int shift = level * 8;
        hist[t] = 0;
        __syncthreads();
        unsigned prefix = s_prefix; int kk = s_k;
        for (int i = t; i < NSUB; i += 256) {
            unsigned u = uv[i];
            bool mm = (level == 3) || ((u >> (shift + 8)) == prefix);
            unsigned bin = mm ? ((u >> shift) & 255u) : 0xFFFFFFFFu;
            // wave-uniform fast path (degenerate levels: all keys same byte)
            unsigned fb = __builtin_amdgcn_readfirstlane(bin);
            unsigned long long bal = __ballot(bin == fb);
            if (bal == ~0ull) {
                if ((t & 63) == 0 && fb != 0xFFFFFFFFu) atomicAdd(&hist[fb], 64);
            } else if (bin != 0xFFFFFFFFu) {
                atomicAdd(&hist[bin], 1);
            }
        }
        __syncthreads();
        sc[t] = hist[t];
        __syncthreads();
        for (int off = 1; off < 256; off <<= 1) {   // suffix sum
            int v = sc[t];
            if (t + off < 256) v += sc[t + off];
            __syncthreads();
            sc[t] = v;
            __syncthreads();
        }
        int gt = (t < 255) ? sc[t + 1] : 0;   // keys strictly above bin t
        if (gt < kk && kk <= gt + hist[t]) {
            s_prefix = (prefix << 8) | (unsigned)t;
            s_k = kk - gt;
        }
        __syncthreads();
    }
    if (t == 0) thr[row] = __uint_as_float(s_prefix);
}

// ---------------------------------------------------------------------------
// Kernel 3: collect candidates >= threshold, one atomic per surviving block
// (<= 64 survivors/row; 99.6% of blocks exit after two scalar loads).
// Key = (valbits << 32) | ~flatidx: descending value then ascending index —
// exactly lax.top_k / numpy tie-break order.
// ---------------------------------------------------------------------------
__global__ __launch_bounds__(256) void k_collect(
    const float* __restrict__ sp, const float* __restrict__ pp,
    const float* __restrict__ cmax4096, const float* __restrict__ thr,
    int* __restrict__ cnt, unsigned long long* __restrict__ cand, int cap)
{
    int c   = blockIdx.x;
    int row = c / NCHUNK;
    float tval = thr[row];
    if (cmax4096[c] < tval) return;   // block-uniform exit

    int cr = c - row * NCHUNK;
    long base = (long)row * ROW + (long)cr * CHUNK;
    int fr    = cr * CHUNK;
    int t = threadIdx.x;
    int g = t >> 5;
    int l = t & 31;
    int subfr = fr + g * SUB;
    float p = pp[row * NLEAF + subfr / VOCAB];

    const float4* sp4 = (const float4*)(sp + base + g * SUB);
    float pr[16];
    int m = 0;
#pragma unroll
    for (int i = 0; i < 4; ++i) {
        float4 v = sp4[l + i * 32];
        pr[i * 4 + 0] = v.x * p;
        pr[i * 4 + 1] = v.y * p;
        pr[i * 4 + 2] = v.z * p;
        pr[i * 4 + 3] = v.w * p;
#pragma unroll
        for (int j = 0; j < 4; ++j) m += (pr[i * 4 + j] >= tval) ? 1 : 0;
    }

    __shared__ int sc2[256];
    __shared__ int sbase;
    sc2[t] = m;
    __syncthreads();
    for (int off = 1; off < 256; off <<= 1) {       // inclusive Hillis-Steele
        int v = sc2[t];
        if (t >= off) v += sc2[t - off];
        __syncthreads();
        sc2[t] = v;
        __syncthreads();
    }
    if (t == 255) sbase = atomicAdd(&cnt[row], sc2[255]);
    __syncthreads();

    if (m > 0) {
        int pos = sbase + sc2[t] - m;
#pragma unroll
        for (int i = 0; i < 4; ++i) {
#pragma unroll
            for (int j = 0; j < 4; ++j) {
                float v = pr[i * 4 + j];
                if (v >= tval) {
                    if (pos < cap) {
                        unsigned fb = __float_as_uint(v);
                        unsigned fi = (unsigned)(subfr + (l + i * 32) * 4 + j);
                        cand[(long)row * cap + pos] =
                            ((unsigned long long)fb << 32) |
                            (unsigned long long)(0xFFFFFFFFu - fi);
                    }
                    pos++;
                }
            }
        }
    }
}

// ---------------------------------------------------------------------------
// Kernel 4: per row, exact 64th-largest 64-bit key via 8-level radix select
// (keys unique -> exactly 64 keys >= K64), compact, rank-sort, write outputs
// [token_ids | topk_probs | parent_indices] as float32.
// ---------------------------------------------------------------------------
__global__ __launch_bounds__(256) void k_final(
    const int* __restrict__ cnt, const unsigned long long* __restrict__ cand,
    int cap, float* __restrict__ out)
{
    int row = blockIdx.x;
    int t = threadIdx.x;
    int nc = cnt[row]; if (nc > cap) nc = cap;
    const unsigned long long* c = cand + (long)row * cap;

    __shared__ int hist[256], sc[256];
    __shared__ unsigned long long s_prefix;
    __shared__ int s_k;
    __shared__ unsigned long long stop[TOPK];
    __shared__ int s_ntop;
    if (t == 0) { s_prefix = 0ull; s_k = TOPK; s_ntop = 0; }
    __syncthreads();

    for (int level = 7; level >= 0; --level) {
        int shift = level * 8;
        hist[t] = 0;
        __syncthreads();
        unsigned long long prefix = s_prefix; int kk = s_k;
        for (int i = t; i < nc; i += 256) {
            unsigned long long u = c[i];
            bool mm = (level == 7) || ((u >> (shift + 8)) == prefix);
            unsigned bin = mm ? (unsigned)((u >> shift) & 255ull) : 0xFFFFFFFFu;
            if (bin != 0xFFFFFFFFu) atomicAdd(&hist[bin], 1);
        }
        __syncthreads();
        sc[t] = hist[t];
        __syncthreads();
        for (int off = 1; off < 256; off <<= 1) {
            int v = sc[t];
            if (t + off < 256) v += sc[t + off];
            __syncthreads();
            sc[t] = v;
            __syncthreads();
        }
        int gt = (t < 255) ? sc[t + 1] : 0;
        if (gt < kk && kk <= gt + hist[t]) {
            s_prefix = (prefix << 8) | (unsigned long long)t;
            s_k = kk - gt;
        }
        __syncthreads();
    }

    unsigned long long K64 = s_prefix;   // exact 64th-largest key
    for (int i = t; i < nc; i += 256) {
        unsigned long long u = c[i];
        if (u >= K64) {
            int p = atomicAdd(&s_ntop, 1);
            if (p < TOPK) stop[p] = u;
        }
    }
    __syncthreads();

    int ntop = s_ntop; if (ntop > TOPK) ntop = TOPK;
    if (t < ntop) {
        unsigned long long mykey = stop[t];
        int rank = 0;
        for (int j = 0; j < ntop; ++j) rank += (stop[j] > mykey) ? 1 : 0;
        unsigned fi = 0xFFFFFFFFu - (unsigned)(mykey & 0xFFFFFFFFull);
        float val = __uint_as_float((unsigned)(mykey >> 32));
        int tok  = (int)(fi % VOCAB);
        int leaf = (int)(fi / VOCAB);
        out[row * TOPK + rank]                    = (float)tok;
        out[BATCH * TOPK + row * TOPK + rank]     = val;
        out[2 * BATCH * TOPK + row * TOPK + rank] = (float)leaf;
    }
}

extern "C" void kernel_launch(void* const* d_in, const int* in_sizes, int n_in,
                              void* d_out, int out_size, void* d_ws, size_t ws_size,
                              hipStream_t stream) {
    const float* sp = (const float*)d_in[0];   // [8,64,128000] f32
    const float* pp = (const float*)d_in[1];   // [8,64] f32
    float* out = (float*)d_out;                // 1536 f32

    char* ws = (char*)d_ws;
    float* cmax512  = (float*)ws;                          // 8*16000 f32 = 512000 B
    float* cmax4096 = (float*)(ws + 512000);               // 16000 f32  =  64000 B
    float* thr      = (float*)(ws + 576000);               // 8 f32
    int*   cnt      = (int*)(ws + 576032);                 // 8 i32
    unsigned long long* cand = (unsigned long long*)(ws + 589824);

    int cap = 16384;
    size_t need = 589824 + (size_t)BATCH * (size_t)cap * 8;
    if (ws_size < need) {
        cap = (int)((ws_size > 589824 ? (ws_size - 589824) : 0) / (BATCH * 8));
        if (cap < 256) cap = 256;
    }

    k_chunkmax <<<BATCH * NCHUNK, 256, 0, stream>>>(sp, pp, cmax512, cmax4096);
    k_threshold<<<BATCH,          256, 0, stream>>>(cmax512, thr, cnt);
    k_collect  <<<BATCH * NCHUNK, 256, 0, stream>>>(sp, pp, cmax4096, thr, cnt, cand, cap);
    k_final    <<<BATCH,          256, 0, stream>>>(cnt, cand, cap, out);
}